// Round 1
// baseline (1691.962 us; speedup 1.0000x reference)
//
#include <hip/hip_runtime.h>

#define C 8
#define K 27
#define VPT 4
#define BLOCK 256

__global__ __launch_bounds__(BLOCK) void sconv_kernel(
    const float* __restrict__ x,      // [N,8] input features
    const float* __restrict__ W,      // [27,8,8] weights for this layer
    const int*   __restrict__ nbr,    // [N,27] neighbor map, -1 = missing
    const float* __restrict__ resid,  // [N,8] residual to add, or nullptr
    float*       __restrict__ y,      // [N,8] output
    int n, int do_relu)
{
    __shared__ float w_lds[K * C * C];
    for (int i = threadIdx.x; i < K * C * C; i += BLOCK) w_lds[i] = W[i];
    __syncthreads();

    const int base = blockIdx.x * (BLOCK * VPT) + threadIdx.x;

    float acc[VPT][C];
    int vox[VPT];
#pragma unroll
    for (int v = 0; v < VPT; ++v) {
        vox[v] = base + v * BLOCK;
#pragma unroll
        for (int d = 0; d < C; ++d) acc[v][d] = 0.f;
    }

    for (int k = 0; k < K; ++k) {
        float4 f0[VPT], f1[VPT];
#pragma unroll
        for (int v = 0; v < VPT; ++v) {
            f0[v] = make_float4(0.f, 0.f, 0.f, 0.f);
            f1[v] = make_float4(0.f, 0.f, 0.f, 0.f);
            if (vox[v] < n) {
                int idx = nbr[(size_t)vox[v] * K + k];
                if (idx >= 0) {
                    const float4* p = (const float4*)(x + (size_t)idx * C);
                    f0[v] = p[0];
                    f1[v] = p[1];
                }
            }
        }
        const float4* wk = (const float4*)(w_lds + k * C * C);
#pragma unroll
        for (int c = 0; c < C; ++c) {
            float4 wlo = wk[c * 2];
            float4 whi = wk[c * 2 + 1];
#pragma unroll
            for (int v = 0; v < VPT; ++v) {
                float a = (c < 4) ? (&f0[v].x)[c] : (&f1[v].x)[c - 4];
                acc[v][0] += a * wlo.x;
                acc[v][1] += a * wlo.y;
                acc[v][2] += a * wlo.z;
                acc[v][3] += a * wlo.w;
                acc[v][4] += a * whi.x;
                acc[v][5] += a * whi.y;
                acc[v][6] += a * whi.z;
                acc[v][7] += a * whi.w;
            }
        }
    }

#pragma unroll
    for (int v = 0; v < VPT; ++v) {
        if (vox[v] >= n) continue;
        float4 o0 = make_float4(acc[v][0], acc[v][1], acc[v][2], acc[v][3]);
        float4 o1 = make_float4(acc[v][4], acc[v][5], acc[v][6], acc[v][7]);
        if (resid) {
            const float4* r = (const float4*)(resid + (size_t)vox[v] * C);
            float4 r0 = r[0], r1 = r[1];
            o0.x += r0.x; o0.y += r0.y; o0.z += r0.z; o0.w += r0.w;
            o1.x += r1.x; o1.y += r1.y; o1.z += r1.z; o1.w += r1.w;
        }
        if (do_relu) {
            o0.x = fmaxf(o0.x, 0.f); o0.y = fmaxf(o0.y, 0.f);
            o0.z = fmaxf(o0.z, 0.f); o0.w = fmaxf(o0.w, 0.f);
            o1.x = fmaxf(o1.x, 0.f); o1.y = fmaxf(o1.y, 0.f);
            o1.z = fmaxf(o1.z, 0.f); o1.w = fmaxf(o1.w, 0.f);
        }
        float4* yp = (float4*)(y + (size_t)vox[v] * C);
        yp[0] = o0;
        yp[1] = o1;
    }
}

extern "C" void kernel_launch(void* const* d_in, const int* in_sizes, int n_in,
                              void* d_out, int out_size, void* d_ws, size_t ws_size,
                              hipStream_t stream) {
    const float* feats0 = (const float*)d_in[0];
    const float* feats1 = (const float*)d_in[1];
    const float* W0     = (const float*)d_in[2];
    const float* W1     = (const float*)d_in[3];
    const int*   nbr0   = (const int*)d_in[4];
    const int*   nbr1   = (const int*)d_in[5];
    float* out = (float*)d_out;
    float* tmp = (float*)d_ws;  // N*8 floats = 16 MB scratch

    const int n = in_sizes[0] / C;  // 500000
    dim3 block(BLOCK);
    dim3 grid((n + BLOCK * VPT - 1) / (BLOCK * VPT));

    for (int g = 0; g < 2; ++g) {
        const float* x0  = g ? feats1 : feats0;
        const float* Wg  = g ? W1 : W0;
        const int*   nbr = g ? nbr1 : nbr0;
        float* og = out + (size_t)g * n * C;

        // layer 1: og = relu(conv(x0, W[0]))
        sconv_kernel<<<grid, block, 0, stream>>>(x0, Wg, nbr, nullptr, og, n, 1);
        // layer 2: tmp = relu(conv(og, W[1]))
        sconv_kernel<<<grid, block, 0, stream>>>(og, Wg + K * C * C, nbr, nullptr, tmp, n, 1);
        // layer 3: og = conv(tmp, W[2]) + x0
        sconv_kernel<<<grid, block, 0, stream>>>(tmp, Wg + 2 * K * C * C, nbr, x0, og, n, 0);
    }
}

// Round 2
// 472.464 us; speedup vs baseline: 3.5811x; 3.5811x over previous
//
#include <hip/hip_runtime.h>
#include <stdint.h>

#define C 8
#define K 27
#define BLOCK 256
#define VPT 2
#define WSZ (K * C * C)  // 1728 floats per layer

__device__ __forceinline__ uint32_t pack_bf2(float a, float b) {
    uint32_t ua = __float_as_uint(a);
    uint32_t ub = __float_as_uint(b);
    ua = (ua + 0x7FFFu + ((ua >> 16) & 1u)) >> 16;
    ub = (ub + 0x7FFFu + ((ub >> 16) & 1u)) & 0xFFFF0000u;
    return ua | ub;  // lo half = bf16(a), hi half = bf16(b)
}

__global__ __launch_bounds__(BLOCK) void to_bf16_kernel(
    const float4* __restrict__ x, uint4* __restrict__ t, int n)
{
    int i = blockIdx.x * BLOCK + threadIdx.x;
    if (i >= n) return;
    float4 a = x[(size_t)i * 2], b = x[(size_t)i * 2 + 1];
    uint4 o;
    o.x = pack_bf2(a.x, a.y);
    o.y = pack_bf2(a.z, a.w);
    o.z = pack_bf2(b.x, b.y);
    o.w = pack_bf2(b.z, b.w);
    t[i] = o;
}

__global__ __launch_bounds__(BLOCK) void transpose_nbr_kernel(
    const int* __restrict__ nbr, int* __restrict__ nbrT, int n)
{
    int i = blockIdx.x * BLOCK + threadIdx.x;
    if (i >= n) return;
#pragma unroll
    for (int k = 0; k < K; ++k)
        nbrT[(size_t)k * n + i] = nbr[(size_t)i * K + k];
}

// xt: bf16-packed feature table [n] of uint4 (8 bf16). yout: bf16 table or fp32 rows.
template<int RELU, int OUTBF16, int NBRT>
__global__ __launch_bounds__(BLOCK) void sconv_kernel(
    const uint4* __restrict__ xt, const float* __restrict__ Wl,
    const int* __restrict__ nb, const float* __restrict__ resid,
    void* __restrict__ yout, int n)
{
    __shared__ float w_lds[WSZ];
    for (int i = threadIdx.x; i < WSZ; i += BLOCK) w_lds[i] = Wl[i];
    __syncthreads();

    int vox[VPT];
    float acc[VPT][C];
#pragma unroll
    for (int v = 0; v < VPT; ++v) {
        vox[v] = blockIdx.x * (BLOCK * VPT) + v * BLOCK + threadIdx.x;
#pragma unroll
        for (int d = 0; d < C; ++d) acc[v][d] = 0.f;
    }

#pragma unroll 1
    for (int k = 0; k < K; ++k) {
        uint4 g[VPT];
#pragma unroll
        for (int v = 0; v < VPT; ++v) {
            int id = -1;
            if (vox[v] < n)
                id = NBRT ? nb[(size_t)k * n + vox[v]]
                          : nb[(size_t)vox[v] * K + k];
            g[v] = (id >= 0) ? xt[id] : make_uint4(0u, 0u, 0u, 0u);
        }
        const float4* wk = (const float4*)(w_lds + k * C * C);
#pragma unroll
        for (int c = 0; c < C; ++c) {
            float4 wlo = wk[c * 2], whi = wk[c * 2 + 1];
#pragma unroll
            for (int v = 0; v < VPT; ++v) {
                uint32_t w32 = (&g[v].x)[c >> 1];
                float a = (c & 1) ? __uint_as_float(w32 & 0xFFFF0000u)
                                  : __uint_as_float(w32 << 16);
                acc[v][0] += a * wlo.x; acc[v][1] += a * wlo.y;
                acc[v][2] += a * wlo.z; acc[v][3] += a * wlo.w;
                acc[v][4] += a * whi.x; acc[v][5] += a * whi.y;
                acc[v][6] += a * whi.z; acc[v][7] += a * whi.w;
            }
        }
    }

#pragma unroll
    for (int v = 0; v < VPT; ++v) {
        if (vox[v] >= n) continue;
#pragma unroll
        for (int d = 0; d < C; ++d)
            if (RELU) acc[v][d] = fmaxf(acc[v][d], 0.f);
        if (OUTBF16) {
            uint4 o;
            o.x = pack_bf2(acc[v][0], acc[v][1]);
            o.y = pack_bf2(acc[v][2], acc[v][3]);
            o.z = pack_bf2(acc[v][4], acc[v][5]);
            o.w = pack_bf2(acc[v][6], acc[v][7]);
            ((uint4*)yout)[vox[v]] = o;
        } else {
            float4 o0 = make_float4(acc[v][0], acc[v][1], acc[v][2], acc[v][3]);
            float4 o1 = make_float4(acc[v][4], acc[v][5], acc[v][6], acc[v][7]);
            const float4* r = (const float4*)(resid + (size_t)vox[v] * C);
            float4 r0 = r[0], r1 = r[1];
            o0.x += r0.x; o0.y += r0.y; o0.z += r0.z; o0.w += r0.w;
            o1.x += r1.x; o1.y += r1.y; o1.z += r1.z; o1.w += r1.w;
            float4* yp = (float4*)((float*)yout + (size_t)vox[v] * C);
            yp[0] = o0; yp[1] = o1;
        }
    }
}

extern "C" void kernel_launch(void* const* d_in, const int* in_sizes, int n_in,
                              void* d_out, int out_size, void* d_ws, size_t ws_size,
                              hipStream_t stream) {
    const float* feats0 = (const float*)d_in[0];
    const float* feats1 = (const float*)d_in[1];
    const float* W0     = (const float*)d_in[2];
    const float* W1     = (const float*)d_in[3];
    const int*   nbr0   = (const int*)d_in[4];
    const int*   nbr1   = (const int*)d_in[5];
    float* out = (float*)d_out;

    const int n = in_sizes[0] / C;  // 500000
    uint4* bufA = (uint4*)d_ws;              // n * 16 B
    uint4* bufB = bufA + n;                  // n * 16 B
    size_t tbl_bytes = (size_t)n * 16 * 2;
    int* nbrT = (int*)((char*)d_ws + tbl_bytes);
    const bool useT = ws_size >= tbl_bytes + (size_t)n * K * 4;

    dim3 blk(BLOCK);
    int gridc = (n + BLOCK - 1) / BLOCK;
    int gridv = (n + BLOCK * VPT - 1) / (BLOCK * VPT);

    for (int g = 0; g < 2; ++g) {
        const float* x0  = g ? feats1 : feats0;
        const float* Wg  = g ? W1 : W0;
        const int*   nbr = g ? nbr1 : nbr0;
        float* og = out + (size_t)g * n * C;

        to_bf16_kernel<<<gridc, blk, 0, stream>>>((const float4*)x0, bufA, n);
        if (useT) {
            transpose_nbr_kernel<<<gridc, blk, 0, stream>>>(nbr, nbrT, n);
            sconv_kernel<1, 1, 1><<<gridv, blk, 0, stream>>>(bufA, Wg,            nbrT, nullptr, bufB, n);
            sconv_kernel<1, 1, 1><<<gridv, blk, 0, stream>>>(bufB, Wg + WSZ,      nbrT, nullptr, bufA, n);
            sconv_kernel<0, 0, 1><<<gridv, blk, 0, stream>>>(bufA, Wg + 2 * WSZ,  nbrT, x0,      og,   n);
        } else {
            sconv_kernel<1, 1, 0><<<gridv, blk, 0, stream>>>(bufA, Wg,            nbr,  nullptr, bufB, n);
            sconv_kernel<1, 1, 0><<<gridv, blk, 0, stream>>>(bufB, Wg + WSZ,      nbr,  nullptr, bufA, n);
            sconv_kernel<0, 0, 0><<<gridv, blk, 0, stream>>>(bufA, Wg + 2 * WSZ,  nbr,  x0,      og,   n);
        }
    }
}